// Round 1
// baseline (574.654 us; speedup 1.0000x reference)
//
#include <hip/hip_runtime.h>
#include <stdint.h>

using u16 = unsigned short;
typedef u16   u16x8  __attribute__((ext_vector_type(8)));
typedef u16   u16x4  __attribute__((ext_vector_type(4)));
typedef short bf16x8 __attribute__((ext_vector_type(8)));
typedef float f32x4  __attribute__((ext_vector_type(4)));

#define DEVI static __device__ __forceinline__

// sizes (fixed for this problem)
// B=16, C=1024, HW=48*48=2304, MID=256, N3=768 (f|g|h stacked)

DEVI u16 f2bf(float f) {                       // RNE float->bf16
    union { float f; uint32_t u; } v; v.f = f;
    return (u16)((v.u + 0x7fffu + ((v.u >> 16) & 1u)) >> 16);
}

DEVI f32x4 mfma16(bf16x8 a, bf16x8 b, f32x4 c) {
    return __builtin_amdgcn_mfma_f32_16x16x32_bf16(a, b, c, 0, 0, 0);
}

// LDS tile readers; layout: [row][8*spr u16], logical slot s stored at s^(row&7)
DEVI bf16x8 frag64(const u16* base, int row, int slot) {   // 64 u16 per row (8 slots)
    return *(const bf16x8*)(base + row * 64 + ((slot ^ (row & 7)) << 3));
}
DEVI bf16x8 frag256(const u16* base, int row, int slot) {  // 256 u16 per row (32 slots)
    return *(const bf16x8*)(base + row * 256 + ((slot ^ (row & 7)) << 3));
}

// ---------------------------------------------------------------- prep
// W3bf[768][1024] = [Wf;Wg;Wh] bf16; Wvbf[1024][256] bf16;
// alpha/beta[768]: BN fold; softmax scale (1/16) folded into f rows.
__global__ __launch_bounds__(256) void k_prep(
    const float* __restrict__ Wf, const float* __restrict__ bfp,
    const float* __restrict__ gf, const float* __restrict__ btf,
    const float* __restrict__ mf, const float* __restrict__ vf,
    const float* __restrict__ Wg, const float* __restrict__ bg,
    const float* __restrict__ gg, const float* __restrict__ btg,
    const float* __restrict__ mg, const float* __restrict__ vg,
    const float* __restrict__ Wh, const float* __restrict__ bh,
    const float* __restrict__ Wv,
    u16* __restrict__ W3bf, u16* __restrict__ Wvbf,
    float* __restrict__ alpha, float* __restrict__ beta)
{
    int tid = blockIdx.x * 256 + threadIdx.x;
    if (tid < 768 * 1024) {
        int n = tid >> 10, k = tid & 1023;
        float w = (n < 256) ? Wf[n * 1024 + k]
                : (n < 512) ? Wg[(n - 256) * 1024 + k]
                            : Wh[(n - 512) * 1024 + k];
        W3bf[tid] = f2bf(w);
    } else if (tid < 768 * 1024 + 256 * 1024) {
        int i = tid - 768 * 1024;
        Wvbf[i] = f2bf(Wv[i]);
    } else if (tid < 768 * 1024 + 256 * 1024 + 768) {
        int n = tid - (768 * 1024 + 256 * 1024);
        const float EPS = 1e-5f, SC = 0.0625f;  // mid^-0.5
        float a, be;
        if (n < 256) {
            float inv = gf[n] / sqrtf(vf[n] + EPS);
            a  = inv * SC;
            be = (bfp[n] * inv + btf[n] - mf[n] * inv) * SC;
        } else if (n < 512) {
            int m = n - 256;
            float inv = gg[m] / sqrtf(vg[m] + EPS);
            a  = inv;
            be = bg[m] * inv + btg[m] - mg[m] * inv;
        } else { a = 1.0f; be = bh[n - 512]; }
        alpha[n] = a; beta[n] = be;
    }
}

// ---------------------------------------------------------------- x -> xT (bf16)
// x[b][c][i] fp32 -> xT[b][i][c] bf16  (xT lives in d_out scratch)
__global__ __launch_bounds__(256) void k_transpose(
    const float* __restrict__ x, u16* __restrict__ xT)
{
    __shared__ __align__(16) u16 tile[64 * 68];   // [i_local][c_local], pad 68
    const int t  = threadIdx.x;
    const int it = blockIdx.x;   // 0..35
    const int ct = blockIdx.y;   // 0..15
    const int b  = blockIdx.z;   // 0..15
    const size_t xbase = ((size_t)(b * 1024 + ct * 64)) * 2304 + (size_t)it * 64;
    #pragma unroll
    for (int q = 0; q < 4; ++q) {
        int idx = q * 256 + t;
        int cl = idx >> 4, i4 = idx & 15;
        float4 v = *(const float4*)(x + xbase + (size_t)cl * 2304 + i4 * 4);
        tile[(i4 * 4 + 0) * 68 + cl] = f2bf(v.x);
        tile[(i4 * 4 + 1) * 68 + cl] = f2bf(v.y);
        tile[(i4 * 4 + 2) * 68 + cl] = f2bf(v.z);
        tile[(i4 * 4 + 3) * 68 + cl] = f2bf(v.w);
    }
    __syncthreads();
    const size_t obase = ((size_t)(b * 2304 + it * 64)) * 1024 + (size_t)ct * 64;
    #pragma unroll
    for (int q = 0; q < 4; ++q) {
        int idx = q * 256 + t;
        int il = idx >> 4, c4 = idx & 15;
        u16x4 w = *(const u16x4*)(&tile[il * 68 + c4 * 4]);
        *(u16x4*)(xT + obase + (size_t)il * 1024 + c4 * 4) = w;
    }
}

// ---------------------------------------------------------------- h -> HT
// FGH[b*2304+j][512+m] -> HT[b][m][j]  (k-contiguous V^T for PV MFMA)
__global__ __launch_bounds__(256) void k_htrans(
    const u16* __restrict__ FGH, u16* __restrict__ HT)
{
    __shared__ __align__(16) u16 tile[64 * 68];   // [m_local][j_local]
    const int t  = threadIdx.x;
    const int jt = blockIdx.x;   // 0..35
    const int mt = blockIdx.y;   // 0..3
    const int b  = blockIdx.z;
    const u16* src = FGH + ((size_t)b * 2304 + jt * 64) * 768 + 512 + mt * 64;
    #pragma unroll
    for (int q = 0; q < 4; ++q) {
        int idx = q * 256 + t;
        int j = idx >> 4, m4 = idx & 15;
        u16x4 v = *(const u16x4*)(src + (size_t)j * 768 + m4 * 4);
        tile[(m4 * 4 + 0) * 68 + j] = v[0];
        tile[(m4 * 4 + 1) * 68 + j] = v[1];
        tile[(m4 * 4 + 2) * 68 + j] = v[2];
        tile[(m4 * 4 + 3) * 68 + j] = v[3];
    }
    __syncthreads();
    u16* dst = HT + ((size_t)b * 256 + mt * 64) * 2304 + (size_t)jt * 64;
    #pragma unroll
    for (int q = 0; q < 4; ++q) {
        int idx = q * 256 + t;
        int m = idx >> 4, j4 = idx & 15;
        u16x4 w = *(const u16x4*)(&tile[m * 68 + j4 * 4]);
        *(u16x4*)(dst + (size_t)m * 2304 + j4 * 4) = w;
    }
}

// ---------------------------------------------------------------- NT GEMM 128x128, BK=64
// C[m][n] = sum_k A[m][k]*B[n][k].  MODE 0: fgh conv (bf16 out, BN/ReLU epi).
// MODE 1: final conv (fp32 out, +bias +residual), batched via blockIdx.z.
template<int MODE>
__global__ __launch_bounds__(256) void k_gemm(
    const u16* __restrict__ A, const u16* __restrict__ Bm, const int K,
    u16* __restrict__ Cbf, const float* __restrict__ alpha, const float* __restrict__ beta,
    float* __restrict__ Cf, const float* __restrict__ bias, const float* __restrict__ resid)
{
    __shared__ __align__(16) u16 As[128 * 64];
    __shared__ __align__(16) u16 Bs[128 * 64];
    const int t = threadIdx.x;
    const int lane = t & 63, wave = t >> 6;
    const int g = lane >> 4, l15 = lane & 15;
    const int wr = wave >> 1, wc = wave & 1;
    const int m0 = blockIdx.x * 128, n0 = blockIdx.y * 128;
    const int b  = blockIdx.z;

    const u16* Ag = A + (size_t)m0 * K;
    const u16* Bg = (MODE == 0) ? (Bm + (size_t)n0 * K)
                                : (Bm + ((size_t)b * 2304 + n0) * K);

    f32x4 acc[4][4] = {};
    const int nks = K >> 6;
    for (int ks = 0; ks < nks; ++ks) {
        u16x8 va[4], vb[4];
        #pragma unroll
        for (int q = 0; q < 4; ++q) {
            int idx = q * 256 + t;
            int row = idx >> 3, slot = idx & 7;
            size_t go = (size_t)row * K + ks * 64 + slot * 8;
            va[q] = *(const u16x8*)(Ag + go);
            vb[q] = *(const u16x8*)(Bg + go);
        }
        #pragma unroll
        for (int q = 0; q < 4; ++q) {
            int idx = q * 256 + t;
            int row = idx >> 3, slot = idx & 7;
            int so = row * 64 + ((slot ^ (row & 7)) << 3);
            *(u16x8*)(&As[so]) = va[q];
            *(u16x8*)(&Bs[so]) = vb[q];
        }
        __syncthreads();
        #pragma unroll
        for (int kk = 0; kk < 2; ++kk) {
            const int slot = kk * 4 + g;
            bf16x8 af[4], bfv[4];
            #pragma unroll
            for (int f = 0; f < 4; ++f) af[f]  = frag64(As, wr * 64 + f * 16 + l15, slot);
            #pragma unroll
            for (int f = 0; f < 4; ++f) bfv[f] = frag64(Bs, wc * 64 + f * 16 + l15, slot);
            #pragma unroll
            for (int fm = 0; fm < 4; ++fm)
                #pragma unroll
                for (int fn = 0; fn < 4; ++fn)
                    acc[fm][fn] = mfma16(af[fm], bfv[fn], acc[fm][fn]);
        }
        __syncthreads();
    }

    if (MODE == 0) {
        #pragma unroll
        for (int fn = 0; fn < 4; ++fn) {
            const int n = n0 + wc * 64 + fn * 16 + l15;
            const float al = alpha[n], be = beta[n];
            const bool dorelu = (n < 512);
            #pragma unroll
            for (int fm = 0; fm < 4; ++fm)
                #pragma unroll
                for (int r = 0; r < 4; ++r) {
                    const int row = m0 + wr * 64 + fm * 16 + 4 * g + r;
                    float y = acc[fm][fn][r] * al + be;
                    if (dorelu) y = fmaxf(y, 0.0f);
                    Cbf[(size_t)row * 768 + n] = f2bf(y);
                }
        }
    } else {
        const size_t ob = (size_t)b * 1024 * 2304;
        #pragma unroll
        for (int fm = 0; fm < 4; ++fm)
            #pragma unroll
            for (int r = 0; r < 4; ++r) {
                const int row = m0 + wr * 64 + fm * 16 + 4 * g + r;   // c
                const float bb = bias[row];
                #pragma unroll
                for (int fn = 0; fn < 4; ++fn) {
                    const int n = n0 + wc * 64 + fn * 16 + l15;        // i
                    const size_t o = ob + (size_t)row * 2304 + n;
                    Cf[o] = acc[fm][fn][r] + bb + resid[o];
                }
            }
    }
}

// ---------------------------------------------------------------- pass A: row stats
// per (b, q-tile of 64): loop all j-tiles, S=Q K^T (scale pre-folded into f),
// online (max, sum exp) per row -> statm/statl.
__global__ __launch_bounds__(256) void k_stats(
    const u16* __restrict__ FGH, float* __restrict__ statm, float* __restrict__ statl)
{
    __shared__ __align__(16) u16 Ks[64 * 256];     // 32 KB, full K-tile [j][k]
    __shared__ float mlbuf[2][64][2];
    const int t = threadIdx.x;
    const int lane = t & 63, wave = t >> 6;
    const int g = lane >> 4, l15 = lane & 15;
    const int wr = wave >> 1, wc = wave & 1;
    const int qt = blockIdx.x, b = blockIdx.y;

    const u16* Qg  = FGH + ((size_t)b * 2304 + qt * 64) * 768;       // f cols 0..255
    const u16* Kg0 = FGH + (size_t)b * 2304 * 768 + 256;             // g cols

    bf16x8 qf[2][8];                                // Q fragments in registers
    #pragma unroll
    for (int fm = 0; fm < 2; ++fm) {
        const u16* qrow = Qg + (size_t)(wr * 32 + fm * 16 + l15) * 768;
        #pragma unroll
        for (int kk = 0; kk < 8; ++kk)
            qf[fm][kk] = *(const bf16x8*)(qrow + kk * 32 + g * 8);
    }

    float m8[8], l8[8];
    #pragma unroll
    for (int s = 0; s < 8; ++s) { m8[s] = -3e38f; l8[s] = 0.0f; }

    #pragma unroll 1
    for (int jt = 0; jt < 36; ++jt) {
        const u16* Kg = Kg0 + (size_t)jt * 64 * 768;
        #pragma unroll
        for (int q = 0; q < 8; ++q) {
            int idx = q * 256 + t;
            int row = idx >> 5, slot = idx & 31;
            u16x8 v = *(const u16x8*)(Kg + (size_t)row * 768 + slot * 8);
            *(u16x8*)(&Ks[row * 256 + ((slot ^ (row & 7)) << 3)]) = v;
        }
        __syncthreads();
        f32x4 acc[2][2] = {};
        #pragma unroll
        for (int kk = 0; kk < 8; ++kk) {
            bf16x8 kf[2];
            #pragma unroll
            for (int fj = 0; fj < 2; ++fj)
                kf[fj] = frag256(Ks, wc * 32 + fj * 16 + l15, kk * 4 + g);
            #pragma unroll
            for (int fm = 0; fm < 2; ++fm)
                #pragma unroll
                for (int fj = 0; fj < 2; ++fj)
                    acc[fm][fj] = mfma16(qf[fm][kk], kf[fj], acc[fm][fj]);
        }
        __syncthreads();
        #pragma unroll
        for (int fm = 0; fm < 2; ++fm)
            #pragma unroll
            for (int r = 0; r < 4; ++r) {
                const int s = fm * 4 + r;
                float v0 = acc[fm][0][r], v1 = acc[fm][1][r];
                float mn = fmaxf(m8[s], fmaxf(v0, v1));
                l8[s] = l8[s] * __expf(m8[s] - mn) + __expf(v0 - mn) + __expf(v1 - mn);
                m8[s] = mn;
            }
    }
    // merge across the 16 lanes of each group (they hold different j, same rows)
    #pragma unroll
    for (int s = 0; s < 8; ++s) {
        float m = m8[s], l = l8[s];
        #pragma unroll
        for (int d = 1; d < 16; d <<= 1) {
            float mo = __shfl_xor(m, d, 64);
            float lo = __shfl_xor(l, d, 64);
            float mn = fmaxf(m, mo);
            l = l * __expf(m - mn) + lo * __expf(mo - mn);
            m = mn;
        }
        m8[s] = m; l8[s] = l;
    }
    #pragma unroll
    for (int s = 0; s < 8; ++s)
        if (l15 == s) {
            int rowl = wr * 32 + (s >> 2) * 16 + 4 * g + (s & 3);
            mlbuf[wc][rowl][0] = m8[s];
            mlbuf[wc][rowl][1] = l8[s];
        }
    __syncthreads();
    if (t < 64) {
        float ma = mlbuf[0][t][0], la = mlbuf[0][t][1];
        float mb = mlbuf[1][t][0], lb = mlbuf[1][t][1];
        float mn = fmaxf(ma, mb);
        float l  = la * __expf(ma - mn) + lb * __expf(mb - mn);
        size_t o = (size_t)b * 2304 + qt * 64 + t;
        statm[o] = mn;
        statl[o] = l;
    }
}

// ---------------------------------------------------------------- pass B: O = softmax(S) V
__global__ __launch_bounds__(256) void k_attnpv(
    const u16* __restrict__ FGH, const u16* __restrict__ HT,
    const float* __restrict__ statm, const float* __restrict__ statl,
    u16* __restrict__ O)
{
    __shared__ __align__(16) u16 Ks[64 * 256];   // 32 KB
    __shared__ __align__(16) u16 Ps[64 * 64];    //  8 KB
    __shared__ __align__(16) u16 Vt[256 * 64];   // 32 KB  (V^T tile [m][j])
    __shared__ float s_m[64], s_il[64];
    const int t = threadIdx.x;
    const int lane = t & 63, wave = t >> 6;
    const int g = lane >> 4, l15 = lane & 15;
    const int wr = wave >> 1, wc = wave & 1;
    const int qt = blockIdx.x, b = blockIdx.y;

    const u16* Qg  = FGH + ((size_t)b * 2304 + qt * 64) * 768;
    const u16* Kg0 = FGH + (size_t)b * 2304 * 768 + 256;

    if (t < 64) {
        size_t o = (size_t)b * 2304 + qt * 64 + t;
        s_m[t]  = statm[o];
        s_il[t] = 1.0f / statl[o];
    }
    __syncthreads();

    bf16x8 qf[2][8];
    #pragma unroll
    for (int fm = 0; fm < 2; ++fm) {
        const u16* qrow = Qg + (size_t)(wr * 32 + fm * 16 + l15) * 768;
        #pragma unroll
        for (int kk = 0; kk < 8; ++kk)
            qf[fm][kk] = *(const bf16x8*)(qrow + kk * 32 + g * 8);
    }

    f32x4 oacc[2][8] = {};
    #pragma unroll 1
    for (int jt = 0; jt < 36; ++jt) {
        const u16* Kg = Kg0 + (size_t)jt * 64 * 768;
        #pragma unroll
        for (int q = 0; q < 8; ++q) {
            int idx = q * 256 + t;
            int row = idx >> 5, slot = idx & 31;
            u16x8 v = *(const u16x8*)(Kg + (size_t)row * 768 + slot * 8);
            *(u16x8*)(&Ks[row * 256 + ((slot ^ (row & 7)) << 3)]) = v;
        }
        __syncthreads();
        f32x4 acc[2][2] = {};
        #pragma unroll
        for (int kk = 0; kk < 8; ++kk) {
            bf16x8 kf[2];
            #pragma unroll
            for (int fj = 0; fj < 2; ++fj)
                kf[fj] = frag256(Ks, wc * 32 + fj * 16 + l15, kk * 4 + g);
            #pragma unroll
            for (int fm = 0; fm < 2; ++fm)
                #pragma unroll
                for (int fj = 0; fj < 2; ++fj)
                    acc[fm][fj] = mfma16(qf[fm][kk], kf[fj], acc[fm][fj]);
        }
        // P = exp(S - m_row) -> LDS (swizzled); stats are final, no rescale needed
        #pragma unroll
        for (int fm = 0; fm < 2; ++fm)
            #pragma unroll
            for (int fj = 0; fj < 2; ++fj)
                #pragma unroll
                for (int r = 0; r < 4; ++r) {
                    int rowl = wr * 32 + fm * 16 + 4 * g + r;
                    int col  = wc * 32 + fj * 16 + l15;
                    float p = __expf(acc[fm][fj][r] - s_m[rowl]);
                    Ps[rowl * 64 + ((((col >> 3) ^ (rowl & 7)) << 3) | (col & 7))] = f2bf(p);
                }
        // stage V^T tile [256 m][64 j] from HT
        const u16* Hg = HT + (size_t)b * 256 * 2304 + (size_t)jt * 64;
        #pragma unroll
        for (int q = 0; q < 8; ++q) {
            int idx = q * 256 + t;
            int row = idx >> 3, slot = idx & 7;
            u16x8 v = *(const u16x8*)(Hg + (size_t)row * 2304 + slot * 8);
            *(u16x8*)(&Vt[row * 64 + ((slot ^ (row & 7)) << 3)]) = v;
        }
        __syncthreads();
        // PV: O[i][m] += P[i][j] * Vt[m][j], waves split (i, m)
        #pragma unroll
        for (int kk = 0; kk < 2; ++kk) {
            const int slot = kk * 4 + g;
            bf16x8 pf[2];
            #pragma unroll
            for (int fm = 0; fm < 2; ++fm)
                pf[fm] = frag64(Ps, wr * 32 + fm * 16 + l15, slot);
            #pragma unroll
            for (int fn = 0; fn < 8; ++fn) {
                bf16x8 vv = frag64(Vt, wc * 128 + fn * 16 + l15, slot);
                #pragma unroll
                for (int fm = 0; fm < 2; ++fm)
                    oacc[fm][fn] = mfma16(pf[fm], vv, oacc[fm][fn]);
            }
        }
        __syncthreads();   // protect Ps/Vt/Ks before next iteration
    }
    const size_t Ob = ((size_t)b * 2304 + (size_t)qt * 64) * 256;
    #pragma unroll
    for (int fm = 0; fm < 2; ++fm)
        #pragma unroll
        for (int r = 0; r < 4; ++r) {
            const int rowl = wr * 32 + fm * 16 + 4 * g + r;
            const float il = s_il[rowl];
            #pragma unroll
            for (int fn = 0; fn < 8; ++fn) {
                const int m = wc * 128 + fn * 16 + l15;
                O[Ob + (size_t)rowl * 256 + m] = f2bf(oacc[fm][fn][r] * il);
            }
        }
}

// ---------------------------------------------------------------- launch
extern "C" void kernel_launch(void* const* d_in, const int* in_sizes, int n_in,
                              void* d_out, int out_size, void* d_ws, size_t ws_size,
                              hipStream_t stream)
{
    const float* x   = (const float*)d_in[0];
    const float* Wf  = (const float*)d_in[1];
    const float* bfp = (const float*)d_in[2];
    const float* gf  = (const float*)d_in[3];
    const float* btf = (const float*)d_in[4];
    const float* mf  = (const float*)d_in[5];
    const float* vf  = (const float*)d_in[6];
    const float* Wg  = (const float*)d_in[7];
    const float* bg  = (const float*)d_in[8];
    const float* gg  = (const float*)d_in[9];
    const float* btg = (const float*)d_in[10];
    const float* mg  = (const float*)d_in[11];
    const float* vg  = (const float*)d_in[12];
    const float* Wh  = (const float*)d_in[13];
    const float* bh  = (const float*)d_in[14];
    const float* Wv  = (const float*)d_in[15];
    const float* bv  = (const float*)d_in[16];
    float* out = (float*)d_out;

    // workspace layout (~38.3 MB)
    char* ws = (char*)d_ws;
    float* statm = (float*)(ws + 0);           // 147456 B
    float* statl = (float*)(ws + 147456);      // 147456 B
    float* alpha = (float*)(ws + 294912);      // 3072 B
    float* beta  = (float*)(ws + 297984);      // 3072 B
    u16*   W3bf  = (u16*)  (ws + 301056);      // 1572864 B
    u16*   Wvbf  = (u16*)  (ws + 1873920);     // 524288 B
    u16*   O     = (u16*)  (ws + 2398208);     // 18874368 B
    u16*   HT    = (u16*)  (ws + 21272576);    // 18874368 B -> 40146944 total

    // d_out doubles as scratch until the final GEMM overwrites it:
    u16* xT  = (u16*)d_out;                        // 75497472 B
    u16* FGH = (u16*)((char*)d_out + 75497472);    // 56623104 B (fits in 151 MB)

    k_prep<<<dim3(4099), 256, 0, stream>>>(Wf, bfp, gf, btf, mf, vf, Wg, bg, gg, btg,
                                           mg, vg, Wh, bh, Wv, W3bf, Wvbf, alpha, beta);
    k_transpose<<<dim3(36, 16, 16), 256, 0, stream>>>(x, xT);
    k_gemm<0><<<dim3(288, 6, 1), 256, 0, stream>>>(xT, W3bf, 1024,
                                                   FGH, alpha, beta,
                                                   nullptr, nullptr, nullptr);
    k_htrans<<<dim3(36, 4, 16), 256, 0, stream>>>(FGH, HT);
    k_stats<<<dim3(36, 16), 256, 0, stream>>>(FGH, statm, statl);
    k_attnpv<<<dim3(36, 16), 256, 0, stream>>>(FGH, HT, statm, statl, O);
    k_gemm<1><<<dim3(8, 18, 16), 256, 0, stream>>>(Wvbf, O, 256,
                                                   nullptr, nullptr, nullptr,
                                                   out, bv, x);
}